// Round 2
// baseline (80.838 us; speedup 1.0000x reference)
//
#include <hip/hip_runtime.h>

typedef __bf16 v8bf __attribute__((ext_vector_type(8)));
typedef __bf16 v4bf __attribute__((ext_vector_type(4)));
typedef float f32x4 __attribute__((ext_vector_type(4)));

#define NB 8
#define MM 128
#define DD 64

// ---------------- Kernel A: rowcol/diag sums + atomic per-n sums + coef repack ----------------
// grid 1024 (= n*128 + i), block 256
__global__ __launch_bounds__(256) void k_prep(
        const float* __restrict__ x, const float* __restrict__ coefs,
        float* __restrict__ rowS, float* __restrict__ colS, float* __restrict__ diagS,
        float* __restrict__ sd, float* __restrict__ sa,
        float* __restrict__ Crep, __bf16* __restrict__ C1T, __bf16* __restrict__ C2T) {
    int b = blockIdx.x, t = threadIdx.x;

    // fold coef repack into first 240 blocks (61440 elements total)
    if (b < 240) {
        int e = b * 256 + t;
        float v = coefs[e];
        int bb = e % 15, q = e / 15;
        int s = q & 63, d = q >> 6;
        Crep[bb * 4096 + s * 64 + d] = v;        // s-major so k_proj can float4 over d
        if (bb == 0) C1T[s * 64 + d] = (__bf16)v;
        else if (bb == 1) C2T[s * 64 + d] = (__bf16)v;
    }

    int n = b >> 7, i = b & 127;
    const float* xn = x + (size_t)n * (MM * MM * DD);
    int d4 = (t & 15) << 2, c = t >> 4;          // 16 d4-slots x 16 j-groups

    f32x4 ar = {0.f, 0.f, 0.f, 0.f}, ac = {0.f, 0.f, 0.f, 0.f};
    for (int j = c; j < MM; j += 16) {
        f32x4 v1 = *(const f32x4*)(xn + (i * MM + j) * DD + d4);   // row i
        f32x4 v2 = *(const f32x4*)(xn + (j * MM + i) * DD + d4);   // col i
        ar += v1; ac += v2;
    }
    __shared__ float red_r[16][64], red_c[16][64];
    *(f32x4*)&red_r[c][d4] = ar;
    *(f32x4*)&red_c[c][d4] = ac;
    __syncthreads();
    if (t < 64) {
        float r = 0.f, cc = 0.f;
        #pragma unroll
        for (int g = 0; g < 16; ++g) { r += red_r[g][t]; cc += red_c[g][t]; }
        float dg = xn[(i * MM + i) * DD + t];
        rowS[b * DD + t] = r;
        colS[b * DD + t] = cc;
        diagS[b * DD + t] = dg;
        atomicAdd(&sd[n * DD + t], dg);
        atomicAdd(&sa[n * DD + t], r);
    }
}

// ---------------- Kernel B: projections F, G, Dd ----------------
// grid 512, block 256: 2 rows/block, threads = (s in 64, c in 2 d-halves, r2 in 2 rows)
__global__ __launch_bounds__(256) void k_proj(
        const float* __restrict__ rowS, const float* __restrict__ colS,
        const float* __restrict__ diagS, const float* __restrict__ sd,
        const float* __restrict__ sa, const float* __restrict__ Crep,
        const float* __restrict__ bias, const float* __restrict__ diag_bias,
        float* __restrict__ F, float* __restrict__ G, float* __restrict__ Dd) {
    int t = threadIdx.x;
    int s = t & 63, c = (t >> 6) & 1, r2 = t >> 7;
    int r = blockIdx.x * 2 + r2;                 // (n,i) flat row, 0..1023
    int n = r >> 7;
    const float* dgp = diagS + r * 64;
    const float* clp = colS + r * 64;
    const float* rwp = rowS + r * 64;
    const float* sdp = sd + n * 64;
    const float* sap = sa + n * 64;

    f32x4 aF = {0.f,0.f,0.f,0.f}, aG = aF, aD = aF;
    #pragma unroll
    for (int dq = 0; dq < 8; ++dq) {
        int d = c * 32 + dq * 4;
        f32x4 dg = *(const f32x4*)(dgp + d);
        f32x4 cl = *(const f32x4*)(clp + d);
        f32x4 rw = *(const f32x4*)(rwp + d);
        f32x4 sdv = *(const f32x4*)(sdp + d);
        f32x4 sav = *(const f32x4*)(sap + d);
        int o = s * 64 + d;
        #define PL(p) (*(const f32x4*)(Crep + (p) * 4096 + o))
        aF += PL(4) * dg + PL(11) * cl + PL(12) * rw + PL(13) * sdv + PL(14) * sav;
        aG += PL(3) * dg + PL(9) * cl + PL(10) * rw;
        aD += PL(2) * dg + PL(6) * rw + PL(7) * cl + PL(5) * sdv + PL(8) * sav;
        #undef PL
    }
    float fF = aF[0] + aF[1] + aF[2] + aF[3];
    float fG = aG[0] + aG[1] + aG[2] + aG[3];
    float fD = aD[0] + aD[1] + aD[2] + aD[3];

    __shared__ float red[2][3][2][64];           // [r2][which][c][s]
    red[r2][0][c][s] = fF;
    red[r2][1][c][s] = fG;
    red[r2][2][c][s] = fD;
    __syncthreads();
    if (t < 128) {
        int rr2 = t >> 6, ss = t & 63;
        int rr = blockIdx.x * 2 + rr2;
        F[rr * 64 + ss]  = red[rr2][0][0][ss] + red[rr2][0][1][ss] + bias[ss];
        G[rr * 64 + ss]  = red[rr2][1][0][ss] + red[rr2][1][1][ss];
        Dd[rr * 64 + ss] = red[rr2][2][0][ss] + red[rr2][2][1][ss] + diag_bias[ss];
    }
}

// ---------------- Kernel C: main MFMA kernel with mirror-pair tiling ----------------
// per n: 192 blocks. b<128: diagonal-tile blocks (P1 only). b in [128,192): i=b-128,
// h=1 off-diagonal blocks computing BOTH (i, 64..127) and (64..127, i).
__global__ __launch_bounds__(256) void k_main(
        const float* __restrict__ x, const float* __restrict__ mask,
        const float* __restrict__ F, const float* __restrict__ G,
        const float* __restrict__ Dd, const __bf16* __restrict__ C1T,
        const __bf16* __restrict__ C2T, float* __restrict__ out) {
    __shared__ __bf16 Xs[64][72];
    __shared__ __bf16 XTs[64][72];
    __shared__ __bf16 C1s[64][72];
    __shared__ __bf16 C2s[64][72];

    int bid = blockIdx.x;
    int n = bid / 192;
    int b = bid % 192;
    int i, h; bool mir;
    if (b < 128) { i = b; h = b >> 6; mir = false; }
    else         { i = b - 128; h = 1; mir = true; }
    int j0 = h << 6;
    int tid = threadIdx.x;

    const float* xn = x + (size_t)n * (MM * MM * DD);
    const float* xid = xn + (i * MM + j0) * DD;

    #pragma unroll
    for (int c = 0; c < 4; ++c) {
        int v = c * 256 + tid;
        float4 f4 = ((const float4*)xid)[v];
        int r = v >> 4, d0 = (v & 15) << 2;
        v4bf bb = {(__bf16)f4.x, (__bf16)f4.y, (__bf16)f4.z, (__bf16)f4.w};
        *(v4bf*)&Xs[r][d0] = bb;
    }
    #pragma unroll
    for (int c = 0; c < 4; ++c) {
        int v = c * 256 + tid;
        int r = v >> 4, d0 = (v & 15) << 2;
        float4 f4 = *(const float4*)(xn + ((size_t)(j0 + r) * MM + i) * DD + d0);
        v4bf bb = {(__bf16)f4.x, (__bf16)f4.y, (__bf16)f4.z, (__bf16)f4.w};
        *(v4bf*)&XTs[r][d0] = bb;
    }
    #pragma unroll
    for (int c = 0; c < 4; ++c) {
        int v = c * 256 + tid;
        int s = v >> 4, d0 = (v & 15) << 2;
        *(v4bf*)&C1s[s][d0] = ((const v4bf*)C1T)[v];
        *(v4bf*)&C2s[s][d0] = ((const v4bf*)C2T)[v];
    }
    __syncthreads();

    int w = tid >> 6, l = tid & 63;
    int lr = l & 15, hi = l >> 4;
    int arow = w * 16 + lr;

    f32x4 acc1[4], acc2[4];
    #pragma unroll
    for (int st = 0; st < 4; ++st) { acc1[st] = (f32x4){0.f,0.f,0.f,0.f}; acc2[st] = (f32x4){0.f,0.f,0.f,0.f}; }

    #pragma unroll
    for (int kk = 0; kk < 2; ++kk) {
        int ko = kk * 32 + hi * 8;
        v8bf a1 = *(const v8bf*)&Xs[arow][ko];
        v8bf a2 = *(const v8bf*)&XTs[arow][ko];
        #pragma unroll
        for (int st = 0; st < 4; ++st) {
            v8bf b1 = *(const v8bf*)&C1s[st * 16 + lr][ko];
            v8bf b2 = *(const v8bf*)&C2s[st * 16 + lr][ko];
            acc1[st] = __builtin_amdgcn_mfma_f32_16x16x32_bf16(a1, b1, acc1[st], 0, 0, 0);
            acc1[st] = __builtin_amdgcn_mfma_f32_16x16x32_bf16(a2, b2, acc1[st], 0, 0, 0);
            if (mir) {
                acc2[st] = __builtin_amdgcn_mfma_f32_16x16x32_bf16(a2, b1, acc2[st], 0, 0, 0);
                acc2[st] = __builtin_amdgcn_mfma_f32_16x16x32_bf16(a1, b2, acc2[st], 0, 0, 0);
            }
        }
    }

    // ---- epilogue P1: out[n, i, j0+r, s]
    int base_i = n * MM + i;
    const float* Fp = F + base_i * 64;
    const float* Dp = Dd + base_i * 64;
    const float* Gn = G + n * MM * 64;
    const float* mrow = mask + (size_t)base_i * MM + j0;
    float* outp = out + ((size_t)base_i * MM + j0) * 64;

    #pragma unroll
    for (int st = 0; st < 4; ++st) {
        int s = st * 16 + lr;
        float Fv = Fp[s];
        float Dv = Dp[s];
        #pragma unroll
        for (int q = 0; q < 4; ++q) {
            int r = w * 16 + hi * 4 + q;
            int j = j0 + r;
            float v = acc1[st][q] + Fv + Gn[j * 64 + s];
            if (i == j) v += Dv;
            v = v > 0.f ? v : 0.01f * v;
            v *= mrow[r];
            outp[(size_t)r * 64 + s] = v;
        }
    }

    // ---- epilogue P2 (mirror): out[n, j0+r, i, s]; here i<64, j>=64 so never diagonal
    if (mir) {
        const float* Gi = G + (n * MM + i) * 64;
        #pragma unroll
        for (int st = 0; st < 4; ++st) {
            int s = st * 16 + lr;
            float Gv = Gi[s];
            #pragma unroll
            for (int q = 0; q < 4; ++q) {
                int r = w * 16 + hi * 4 + q;
                int j = j0 + r;
                int row = n * MM + j;
                float v = acc2[st][q] + F[row * 64 + s] + Gv;
                v = v > 0.f ? v : 0.01f * v;
                v *= mask[(size_t)row * MM + i];
                out[((size_t)row * MM + i) * 64 + s] = v;
            }
        }
    }
}

extern "C" void kernel_launch(void* const* d_in, const int* in_sizes, int n_in,
                              void* d_out, int out_size, void* d_ws, size_t ws_size,
                              hipStream_t stream) {
    const float* x = (const float*)d_in[0];
    // d_in[1] = nobj (unused: config 's' -> no rescale)
    const float* mask = (const float*)d_in[2];
    const float* coefs = (const float*)d_in[3];
    const float* bias = (const float*)d_in[4];
    const float* diag_bias = (const float*)d_in[5];
    float* out = (float*)d_out;

    float* w0 = (float*)d_ws;
    float* rowS = w0;                 // 65536
    float* colS = w0 + 65536;         // 65536
    float* diagS = w0 + 131072;       // 65536
    float* sd = w0 + 196608;          // 512
    float* sa = w0 + 197120;          // 512
    float* F = w0 + 197632;           // 65536
    float* G = w0 + 263168;           // 65536
    float* Dd = w0 + 328704;          // 65536
    float* Crep = w0 + 394240;        // 61440 (s-major [plane][s][d])
    __bf16* C1T = (__bf16*)(w0 + 455680);   // 4096 bf16
    __bf16* C2T = (__bf16*)(w0 + 457728);   // 4096 bf16

    hipMemsetAsync(sd, 0, 4096, stream);    // zero sd+sa (adjacent)
    k_prep<<<dim3(1024), dim3(256), 0, stream>>>(x, coefs, rowS, colS, diagS, sd, sa,
                                                 Crep, C1T, C2T);
    k_proj<<<dim3(512), dim3(256), 0, stream>>>(rowS, colS, diagS, sd, sa, Crep,
                                                bias, diag_bias, F, G, Dd);
    k_main<<<dim3(1536), dim3(256), 0, stream>>>(x, mask, F, G, Dd, C1T, C2T, out);
}

// Round 3
// 37.258 us; speedup vs baseline: 2.1697x; 2.1697x over previous
//
#include <hip/hip_runtime.h>

typedef __bf16 v8bf __attribute__((ext_vector_type(8)));
typedef __bf16 v4bf __attribute__((ext_vector_type(4)));
typedef float f32x4 __attribute__((ext_vector_type(4)));

#define NB 8
#define MM 128
#define DD 64

// ---------------- Kernel A: row/col/diag sums (-> bf16 V) + weight repack ----------------
// grid 1024 (= n*128 + i), block 256
// V[r][k]: k 0..63 = diag, 64..127 = colsum, 128..191 = rowsum   (bf16)
// WT[sg][k]: proj-GEMM B matrix (sg = g*64+s; g: 0=F,1=G,2=Dd; k-groups diag/col/row)
// Wc[sg][k2]: correction weights (k2 0..63: sd-weights, 64..127: sa-weights)
__global__ __launch_bounds__(256) void k_prep(
        const float* __restrict__ x, const float* __restrict__ coefs,
        __bf16* __restrict__ V, __bf16* __restrict__ WT, __bf16* __restrict__ Wc,
        __bf16* __restrict__ C1T, __bf16* __restrict__ C2T) {
    int b = blockIdx.x, t = threadIdx.x;

    // ---- weight repack folded into first 272 blocks ----
    if (b < 144) {                       // WT: 192*192 = 36864
        int e = b * 256 + t;
        int sg = e / 192, k = e % 192;
        int g = sg >> 6, s = sg & 63, kg = k >> 6, d = k & 63;
        // plane tables: F:{diag 4, col 11, row 12}  G:{3,9,10}  Dd:{diag 2, col 7, row 6}
        int plane;
        if (g == 0)      plane = (kg == 0) ? 4 : (kg == 1) ? 11 : 12;
        else if (g == 1) plane = (kg == 0) ? 3 : (kg == 1) ? 9 : 10;
        else             plane = (kg == 0) ? 2 : (kg == 1) ? 7 : 6;
        WT[e] = (__bf16)coefs[d * 960 + s * 15 + plane];
    } else if (b < 240) {                // Wc: 192*128 = 24576
        int e = (b - 144) * 256 + t;
        int sg = e >> 7, k = e & 127;
        int g = sg >> 6, s = sg & 63, d = k & 63;
        float v = 0.f;
        if (g == 0)      v = coefs[d * 960 + s * 15 + (k < 64 ? 13 : 14)];
        else if (g == 2) v = coefs[d * 960 + s * 15 + (k < 64 ? 5 : 8)];
        Wc[e] = (__bf16)v;
    } else if (b < 272) {                // C1T/C2T: 2*4096
        int e = (b - 240) * 256 + t;
        int m = e >> 12, q = e & 4095, s = q >> 6, d = q & 63;
        __bf16 v = (__bf16)coefs[d * 960 + s * 15 + m];
        if (m == 0) C1T[s * 64 + d] = v;
        else        C2T[s * 64 + d] = v;
    }

    // ---- row/col/diag sums ----
    int n = b >> 7, i = b & 127;
    const float* xn = x + (size_t)n * (MM * MM * DD);
    int d4 = (t & 15) << 2, c = t >> 4;

    f32x4 ar = {0.f, 0.f, 0.f, 0.f}, ac = {0.f, 0.f, 0.f, 0.f};
    for (int j = c; j < MM; j += 16) {
        ar += *(const f32x4*)(xn + (i * MM + j) * DD + d4);
        ac += *(const f32x4*)(xn + (j * MM + i) * DD + d4);
    }
    __shared__ float red_r[16][64], red_c[16][64];
    *(f32x4*)&red_r[c][d4] = ar;
    *(f32x4*)&red_c[c][d4] = ac;
    __syncthreads();
    if (t < 64) {
        float r = 0.f, cc = 0.f;
        #pragma unroll
        for (int g = 0; g < 16; ++g) { r += red_r[g][t]; cc += red_c[g][t]; }
        float dg = xn[(i * MM + i) * DD + t];
        V[b * 192 + t]       = (__bf16)dg;
        V[b * 192 + 64 + t]  = (__bf16)cc;
        V[b * 192 + 128 + t] = (__bf16)r;
    }
}

// ---------------- Kernel B: projection GEMM ----------------
// grid 48 (= mt*3 + g; mt: 16 row-tiles of 64, g: 0=F,1=G,2=Dd), block 256 (4 waves)
// O[r][s] = sum_k V[r][k]*WT[g*64+s][k]  + corr[n][s]
// corr[n][s] = bias-ish + sum_d sd[n,d]*Wc[sg][d] + sa[n,d]*Wc[sg][64+d]
__global__ __launch_bounds__(256) void k_proj(
        const __bf16* __restrict__ V, const __bf16* __restrict__ WT,
        const __bf16* __restrict__ Wc, const float* __restrict__ bias,
        const float* __restrict__ diag_bias,
        float* __restrict__ F, float* __restrict__ G, float* __restrict__ Dd) {
    __shared__ __bf16 Vs[64][200];
    __shared__ __bf16 Ws[64][200];
    __shared__ float red[8][64];      // [0..3]=sd partials, [4..7]=sa partials
    __shared__ float sdsa[128];
    __shared__ float corrL[64];

    int bx = blockIdx.x;
    int mt = bx / 3, g = bx % 3;
    int r0 = mt * 64, n = mt >> 1;
    int t = threadIdx.x;

    // stage V tile and W tile (ushort8 = 16B chunks; 1536 chunks each)
    #pragma unroll
    for (int c = 0; c < 6; ++c) {
        int v = c * 256 + t;
        int rr = v / 24, kb = (v % 24) * 8;
        *(v8bf*)&Vs[rr][kb] = *(const v8bf*)&V[(size_t)(r0 + rr) * 192 + kb];
    }
    #pragma unroll
    for (int c = 0; c < 6; ++c) {
        int v = c * 256 + t;
        int rr = v / 24, kb = (v % 24) * 8;
        *(v8bf*)&Ws[rr][kb] = *(const v8bf*)&WT[(size_t)(g * 64 + rr) * 192 + kb];
    }

    // sd/sa partial reduce over this n's 128 V rows (skip for G: no sd/sa terms)
    if (g != 1) {
        int d = t & 63, rg = t >> 6;
        float psd = 0.f, psa = 0.f;
        const __bf16* Vn = V + (size_t)(n * 128) * 192;
        for (int rr = rg * 32; rr < rg * 32 + 32; ++rr) {
            psd += (float)Vn[rr * 192 + d];
            psa += (float)Vn[rr * 192 + 128 + d];
        }
        red[rg][d] = psd;
        red[4 + rg][d] = psa;
    }
    __syncthreads();

    if (g != 1) {
        if (t < 128) {
            int half = t >> 6, d = t & 63;
            sdsa[t] = red[half * 4 + 0][d] + red[half * 4 + 1][d]
                    + red[half * 4 + 2][d] + red[half * 4 + 3][d];
        }
    } else if (t < 64) {
        corrL[t] = 0.f;
    }
    __syncthreads();

    if (g != 1) {
        // corr: wave w handles s = w*16 + (l&15); 4 k-chunks across l>>4; shfl-reduce
        int w = t >> 6, l = t & 63;
        int s = w * 16 + (l & 15), kc = l >> 4;
        const __bf16* wc = Wc + (size_t)(g * 64 + s) * 128 + kc * 32;
        float p = 0.f;
        #pragma unroll
        for (int kk = 0; kk < 32; ++kk) p += sdsa[kc * 32 + kk] * (float)wc[kk];
        p += __shfl_xor(p, 16);
        p += __shfl_xor(p, 32);
        if (l < 16) corrL[s] = p + (g == 0 ? bias[s] : diag_bias[s]);
    }

    // MFMA: wave w -> rows w*16..w*16+15, K = 192
    int w = t >> 6, l = t & 63, lr = l & 15, hi = l >> 4;
    int arow = w * 16 + lr;
    f32x4 acc[4];
    #pragma unroll
    for (int st = 0; st < 4; ++st) acc[st] = (f32x4){0.f, 0.f, 0.f, 0.f};
    #pragma unroll
    for (int kk = 0; kk < 6; ++kk) {
        int ko = kk * 32 + hi * 8;
        v8bf a = *(const v8bf*)&Vs[arow][ko];
        #pragma unroll
        for (int st = 0; st < 4; ++st) {
            v8bf bb = *(const v8bf*)&Ws[st * 16 + lr][ko];
            acc[st] = __builtin_amdgcn_mfma_f32_16x16x32_bf16(a, bb, acc[st], 0, 0, 0);
        }
    }
    __syncthreads();

    float* O = (g == 0) ? F : (g == 1) ? G : Dd;
    #pragma unroll
    for (int st = 0; st < 4; ++st) {
        int s = st * 16 + lr;
        float cv = corrL[s];
        #pragma unroll
        for (int q = 0; q < 4; ++q) {
            int rr = w * 16 + hi * 4 + q;
            O[(size_t)(r0 + rr) * 64 + s] = acc[st][q] + cv;
        }
    }
}

// ---------------- Kernel C: main MFMA kernel with mirror-pair tiling ----------------
__global__ __launch_bounds__(256) void k_main(
        const float* __restrict__ x, const float* __restrict__ mask,
        const float* __restrict__ F, const float* __restrict__ G,
        const float* __restrict__ Dd, const __bf16* __restrict__ C1T,
        const __bf16* __restrict__ C2T, float* __restrict__ out) {
    __shared__ __bf16 Xs[64][72];
    __shared__ __bf16 XTs[64][72];
    __shared__ __bf16 C1s[64][72];
    __shared__ __bf16 C2s[64][72];

    int bid = blockIdx.x;
    int n = bid / 192;
    int b = bid % 192;
    int i, h; bool mir;
    if (b < 128) { i = b; h = b >> 6; mir = false; }
    else         { i = b - 128; h = 1; mir = true; }
    int j0 = h << 6;
    int tid = threadIdx.x;

    const float* xn = x + (size_t)n * (MM * MM * DD);
    const float* xid = xn + (i * MM + j0) * DD;

    #pragma unroll
    for (int c = 0; c < 4; ++c) {
        int v = c * 256 + tid;
        float4 f4 = ((const float4*)xid)[v];
        int r = v >> 4, d0 = (v & 15) << 2;
        v4bf bb = {(__bf16)f4.x, (__bf16)f4.y, (__bf16)f4.z, (__bf16)f4.w};
        *(v4bf*)&Xs[r][d0] = bb;
    }
    #pragma unroll
    for (int c = 0; c < 4; ++c) {
        int v = c * 256 + tid;
        int r = v >> 4, d0 = (v & 15) << 2;
        float4 f4 = *(const float4*)(xn + ((size_t)(j0 + r) * MM + i) * DD + d0);
        v4bf bb = {(__bf16)f4.x, (__bf16)f4.y, (__bf16)f4.z, (__bf16)f4.w};
        *(v4bf*)&XTs[r][d0] = bb;
    }
    #pragma unroll
    for (int c = 0; c < 4; ++c) {
        int v = c * 256 + tid;
        int s = v >> 4, d0 = (v & 15) << 2;
        *(v4bf*)&C1s[s][d0] = ((const v4bf*)C1T)[v];
        *(v4bf*)&C2s[s][d0] = ((const v4bf*)C2T)[v];
    }
    __syncthreads();

    int w = tid >> 6, l = tid & 63;
    int lr = l & 15, hi = l >> 4;
    int arow = w * 16 + lr;

    f32x4 acc1[4], acc2[4];
    #pragma unroll
    for (int st = 0; st < 4; ++st) { acc1[st] = (f32x4){0.f,0.f,0.f,0.f}; acc2[st] = (f32x4){0.f,0.f,0.f,0.f}; }

    #pragma unroll
    for (int kk = 0; kk < 2; ++kk) {
        int ko = kk * 32 + hi * 8;
        v8bf a1 = *(const v8bf*)&Xs[arow][ko];
        v8bf a2 = *(const v8bf*)&XTs[arow][ko];
        #pragma unroll
        for (int st = 0; st < 4; ++st) {
            v8bf b1 = *(const v8bf*)&C1s[st * 16 + lr][ko];
            v8bf b2 = *(const v8bf*)&C2s[st * 16 + lr][ko];
            acc1[st] = __builtin_amdgcn_mfma_f32_16x16x32_bf16(a1, b1, acc1[st], 0, 0, 0);
            acc1[st] = __builtin_amdgcn_mfma_f32_16x16x32_bf16(a2, b2, acc1[st], 0, 0, 0);
            if (mir) {
                acc2[st] = __builtin_amdgcn_mfma_f32_16x16x32_bf16(a2, b1, acc2[st], 0, 0, 0);
                acc2[st] = __builtin_amdgcn_mfma_f32_16x16x32_bf16(a1, b2, acc2[st], 0, 0, 0);
            }
        }
    }

    int base_i = n * MM + i;
    const float* Fp = F + base_i * 64;
    const float* Dp = Dd + base_i * 64;
    const float* Gn = G + n * MM * 64;
    const float* mrow = mask + (size_t)base_i * MM + j0;
    float* outp = out + ((size_t)base_i * MM + j0) * 64;

    #pragma unroll
    for (int st = 0; st < 4; ++st) {
        int s = st * 16 + lr;
        float Fv = Fp[s];
        float Dv = Dp[s];
        #pragma unroll
        for (int q = 0; q < 4; ++q) {
            int r = w * 16 + hi * 4 + q;
            int j = j0 + r;
            float v = acc1[st][q] + Fv + Gn[j * 64 + s];
            if (i == j) v += Dv;
            v = v > 0.f ? v : 0.01f * v;
            v *= mrow[r];
            outp[(size_t)r * 64 + s] = v;
        }
    }

    if (mir) {
        const float* Gi = G + (n * MM + i) * 64;
        #pragma unroll
        for (int st = 0; st < 4; ++st) {
            int s = st * 16 + lr;
            float Gv = Gi[s];
            #pragma unroll
            for (int q = 0; q < 4; ++q) {
                int r = w * 16 + hi * 4 + q;
                int j = j0 + r;
                int row = n * MM + j;
                float v = acc2[st][q] + F[row * 64 + s] + Gv;
                v = v > 0.f ? v : 0.01f * v;
                v *= mask[(size_t)row * MM + i];
                out[((size_t)row * MM + i) * 64 + s] = v;
            }
        }
    }
}

extern "C" void kernel_launch(void* const* d_in, const int* in_sizes, int n_in,
                              void* d_out, int out_size, void* d_ws, size_t ws_size,
                              hipStream_t stream) {
    const float* x = (const float*)d_in[0];
    // d_in[1] = nobj (unused: config 's' -> no rescale)
    const float* mask = (const float*)d_in[2];
    const float* coefs = (const float*)d_in[3];
    const float* bias = (const float*)d_in[4];
    const float* diag_bias = (const float*)d_in[5];
    float* out = (float*)d_out;

    float* w0 = (float*)d_ws;
    float* F = w0;                          // 65536 f32
    float* G = w0 + 65536;                  // 65536 f32
    float* Dd = w0 + 131072;                // 65536 f32
    __bf16* V   = (__bf16*)(w0 + 196608);   // 1024*192 bf16
    __bf16* WT  = (__bf16*)(w0 + 294912);   // 192*192 bf16
    __bf16* Wc  = (__bf16*)(w0 + 313344);   // 192*128 bf16
    __bf16* C1T = (__bf16*)(w0 + 325632);   // 4096 bf16
    __bf16* C2T = (__bf16*)(w0 + 327680);   // 4096 bf16

    k_prep<<<dim3(1024), dim3(256), 0, stream>>>(x, coefs, V, WT, Wc, C1T, C2T);
    k_proj<<<dim3(48), dim3(256), 0, stream>>>(V, WT, Wc, bias, diag_bias, F, G, Dd);
    k_main<<<dim3(1536), dim3(256), 0, stream>>>(x, mask, F, G, Dd, C1T, C2T, out);
}